// Round 2
// baseline (1288.703 us; speedup 1.0000x reference)
//
#include <hip/hip_runtime.h>

#define B_ 8
#define S_ 4096
#define IN_ 64
#define HID_ 512
#define NSTEP 12
#define SP_ (S_ + 2)
#define NP_ (B_ * SP_)
#define NTOT (B_ * S_)

typedef unsigned short u16;
typedef __attribute__((ext_vector_type(8))) short bf16x8;
typedef __attribute__((ext_vector_type(4))) float f32x4;

__device__ __forceinline__ u16 f2bf(float f) {
  unsigned u = __float_as_uint(f);
  u += 0x7fffu + ((u >> 16) & 1u);
  return (u16)(u >> 16);
}

__device__ __forceinline__ void gload16(const void* g, void* l) {
  __builtin_amdgcn_global_load_lds((const __attribute__((address_space(1))) void*)g,
                                   (__attribute__((address_space(3))) void*)l, 16, 0, 0);
}

// ---------------- setup: bf16 conversions + weight transposes + pad-row zeroing ----------------
__global__ void setup_kernel(const float* __restrict__ x, const float* __restrict__ Wc,
                             const float* __restrict__ Wi, const float* __restrict__ Wo,
                             u16* __restrict__ wcb, u16* __restrict__ wib,
                             u16* __restrict__ wob, u16* __restrict__ xbf,
                             u16* __restrict__ h0, u16* __restrict__ h1) {
  const int n_wc = 3 * HID_ * HID_;       // wcb[k][o][i] = Wc[o][i][k]
  const int n_wio = IN_ * HID_;
  const int n_xb = NTOT * IN_;
  const int n_pad = 2 * B_ * 2 * HID_;
  const long total = (long)n_wc + 2 * n_wio + n_xb + n_pad;
  for (long u = (long)blockIdx.x * blockDim.x + threadIdx.x; u < total;
       u += (long)gridDim.x * blockDim.x) {
    long v = u;
    if (v < n_wc) {
      int k = (int)(v / (HID_ * HID_));
      int rem = (int)(v % (HID_ * HID_));
      int o = rem / HID_, i = rem % HID_;
      wcb[v] = f2bf(Wc[((long)o * HID_ + i) * 3 + k]);
    } else if ((v -= n_wc) < n_wio) {      // wib[i][j] = Wi[j][i]
      int i = (int)(v / IN_), j = (int)(v % IN_);
      wib[v] = f2bf(Wi[j * HID_ + i]);
    } else if ((v -= n_wio) < n_wio) {     // wob[j][i] = Wo[i][j]
      int j = (int)(v / HID_), i = (int)(v % HID_);
      wob[v] = f2bf(Wo[i * IN_ + j]);
    } else if ((v -= n_wio) < n_xb) {
      xbf[v] = f2bf(x[v]);
    } else {
      v -= n_xb;                           // zero pad rows (s=-1 and s=S per batch, both buffers)
      int buf = (int)(v / (B_ * 2 * HID_));
      int r = (int)(v % (B_ * 2 * HID_));
      int b = r / (2 * HID_);
      int q = r % (2 * HID_);
      int side = q / HID_, i = q % HID_;
      long p = (long)b * SP_ + (side ? (S_ + 1) : 0);
      (buf ? h1 : h0)[p * HID_ + i] = 0;
    }
  }
}

// ---------------- proj_in: h0[n][i] = x[n][:] @ W_in[:,i] + b_in  (bf16 MFMA, K=64) ----------------
__global__ __launch_bounds__(256, 2) void proj_in_gemm(const u16* __restrict__ xb,
                                                       const u16* __restrict__ wib,
                                                       const float* __restrict__ bin,
                                                       u16* __restrict__ hout) {
  __shared__ __align__(16) u16 Ab[128 * 64];
  __shared__ __align__(16) u16 Bb[128 * 64];
  const int tid = threadIdx.x, wid = tid >> 6, lane = tid & 63;
  const int nt = blockIdx.x, mt = blockIdx.y;
  const int wr = wid >> 1, wcn = wid & 1, fr = lane & 15, fq = lane >> 4;
#pragma unroll
  for (int c = 0; c < 4; ++c) {
    const int ch = wid * 4 + c;
    const int row = ch * 8 + (lane >> 3), cb = (lane & 7) * 8;
    gload16(wib + (mt * 128 + row) * 64 + cb, &Ab[ch * 512]);
    gload16(xb + ((long)nt * 128 + row) * 64 + cb, &Bb[ch * 512]);
  }
  f32x4 acc[4][4];
#pragma unroll
  for (int m = 0; m < 4; ++m)
#pragma unroll
    for (int n = 0; n < 4; ++n) acc[m][n] = {0.f, 0.f, 0.f, 0.f};
  __syncthreads();
#pragma unroll
  for (int t = 0; t < 2; ++t) {
    const int j0 = t * 32;
    bf16x8 af[4], bfv[4];
#pragma unroll
    for (int m = 0; m < 4; ++m)
      af[m] = *(const bf16x8*)&Ab[(wr * 64 + m * 16 + fr) * 64 + j0 + fq * 8];
#pragma unroll
    for (int n = 0; n < 4; ++n)
      bfv[n] = *(const bf16x8*)&Bb[(wcn * 64 + n * 16 + fr) * 64 + j0 + fq * 8];
#pragma unroll
    for (int m = 0; m < 4; ++m)
#pragma unroll
      for (int n = 0; n < 4; ++n)
        acc[m][n] = __builtin_amdgcn_mfma_f32_16x16x32_bf16(af[m], bfv[n], acc[m][n], 0, 0, 0);
  }
  const int n0 = nt * 128;
  const int bb = n0 / S_, s0v = n0 % S_;
  const int prow = bb * SP_ + s0v + 1;
#pragma unroll
  for (int m = 0; m < 4; ++m) {
    const int i = mt * 128 + wr * 64 + m * 16 + fq * 4;
    const float4 bias = *(const float4*)&bin[i];
#pragma unroll
    for (int n = 0; n < 4; ++n) {
      const int nl = wcn * 64 + n * 16 + fr;
      const long p = prow + nl;
      union { u16 q[4]; uint2 v; } u;
      u.q[0] = f2bf(acc[m][n][0] + bias.x);
      u.q[1] = f2bf(acc[m][n][1] + bias.y);
      u.q[2] = f2bf(acc[m][n][2] + bias.z);
      u.q[3] = f2bf(acc[m][n][3] + bias.w);
      *(uint2*)&hout[p * HID_ + i] = u.v;
    }
  }
}

// ---------------- conv step: 256x256 tile, BK=64, 8 waves, counted-vmcnt schedule ----------------
// C[o,n] = relu(sum_{k,i} W[o,i,k] h[i,n+k-1] + b), bf16 in/out.
// LDS: 2 dbuf x (A 256x64 + B 256x64) bf16 = 128 KiB, logical row-major [256][64],
// stored with st-swizzle byte ^= ((byte>>9)&1)<<5 (linear gload_lds dest, pre-swizzled
// global source, swizzled ds_read addrs).
__global__ __launch_bounds__(512, 2) void conv_gemm2(const u16* __restrict__ hin,
                                                     u16* __restrict__ hout,
                                                     const u16* __restrict__ wcb,
                                                     const float* __restrict__ bconv) {
  extern __shared__ __align__(16) u16 smem[];
  const int tid = threadIdx.x;
  const int w = tid >> 6, lane = tid & 63;
  const int wm = w >> 2, wn = w & 3;          // 2 x 4 wave grid; per-wave C = 128 x 64
  const int fr = lane & 15, fq = lane >> 4;
  const int mbase = blockIdx.y * 256;
  const int n0 = blockIdx.x * 256;
  const int bb = n0 / S_, s0 = n0 % S_;
  const int prow0 = bb * SP_ + s0;            // tap-k B rows start at prow0+k

  // staging geometry: thread covers 4 chunks of 16 B per operand per tile.
  // linear LDS byte d = c*8192 + tid*16; logical byte l = swz(d) -> pre-swizzled global src.
  const int tl = (tid * 16) ^ (((tid >> 5) & 1) << 5);
  const int srow = tl >> 7;                   // 0..63 (chunk-local row)
  const int scb = (tl & 127) >> 1;            // element col (mult of 8)
  const int wdst = w * 1024;                  // wave-uniform LDS byte base within chunk

  auto stage = [&](int buf, int t) {
    const int kk = t >> 3;                    // tap
    const int i0 = (t & 7) * 64;              // input-channel slice
    char* A = (char*)smem + (size_t)(buf * 2 + 0) * 32768;
    char* Bv = (char*)smem + (size_t)(buf * 2 + 1) * 32768;
    const u16* ga = wcb + (size_t)kk * (HID_ * HID_) + (size_t)(mbase + srow) * HID_ + i0 + scb;
    const u16* gb = hin + (size_t)(prow0 + kk + srow) * HID_ + i0 + scb;
#pragma unroll
    for (int c = 0; c < 4; ++c) {
      gload16(ga + c * 64 * HID_, A + c * 8192 + wdst);
      gload16(gb + c * 64 * HID_, Bv + c * 8192 + wdst);
    }
  };

  f32x4 acc[8][4];
#pragma unroll
  for (int m = 0; m < 8; ++m)
#pragma unroll
    for (int n = 0; n < 4; ++n) acc[m][n] = {0.f, 0.f, 0.f, 0.f};

  stage(0, 0);
  stage(1, 1);

  // ds_read base offsets (loop-invariant): byte = row*128 + k*64 + fq*16, swizzle flips
  // bit5 iff row bit2 (= fr bit2) -> per-lane constant XOR.
  const int arow = (wm * 128 + fr) * 128 + fq * 16;
  const int brow = (wn * 64 + fr) * 128 + fq * 16;
  const int swzb = ((fr >> 2) & 1) << 5;

#pragma unroll 2
  for (int t = 0; t < 24; ++t) {
    const int buf = t & 1;
    const char* A = (const char*)smem + (size_t)(buf * 2 + 0) * 32768;
    const char* Bv = (const char*)smem + (size_t)(buf * 2 + 1) * 32768;

    // tile t complete in LDS; tile t+1's 8 loads may stay in flight
    if (t < 23) { asm volatile("s_waitcnt vmcnt(8)" ::: "memory"); }
    else        { asm volatile("s_waitcnt vmcnt(0)" ::: "memory"); }
    __builtin_amdgcn_sched_barrier(0);
    __builtin_amdgcn_s_barrier();
    __builtin_amdgcn_sched_barrier(0);

    bf16x8 a0[2][4], a1[2][4], bv0[2][2], bv1[2][2];
    // group 1: A-half0 (8) + B-half0 (4)  -> first 12
#pragma unroll
    for (int k = 0; k < 2; ++k)
#pragma unroll
      for (int m = 0; m < 4; ++m)
        a0[k][m] = *(const bf16x8*)(A + ((arow + m * 2048 + k * 64) ^ swzb));
#pragma unroll
    for (int k = 0; k < 2; ++k)
#pragma unroll
      for (int n = 0; n < 2; ++n)
        bv0[k][n] = *(const bf16x8*)(Bv + ((brow + n * 2048 + k * 64) ^ swzb));
    __builtin_amdgcn_sched_barrier(0);
    // group 2: B-half1 (4)
#pragma unroll
    for (int k = 0; k < 2; ++k)
#pragma unroll
      for (int n = 0; n < 2; ++n)
        bv1[k][n] = *(const bf16x8*)(Bv + ((brow + (n + 2) * 2048 + k * 64) ^ swzb));
    __builtin_amdgcn_sched_barrier(0);
    // group 3: A-half1 (8)
#pragma unroll
    for (int k = 0; k < 2; ++k)
#pragma unroll
      for (int m = 0; m < 4; ++m)
        a1[k][m] = *(const bf16x8*)(A + ((arow + (m + 4) * 2048 + k * 64) ^ swzb));
    __builtin_amdgcn_sched_barrier(0);

    // Q00: m0-3 x n0-1
    asm volatile("s_waitcnt lgkmcnt(12)" ::: "memory");
    __builtin_amdgcn_sched_barrier(0);
    __builtin_amdgcn_s_setprio(1);
#pragma unroll
    for (int k = 0; k < 2; ++k)
#pragma unroll
      for (int m = 0; m < 4; ++m)
#pragma unroll
        for (int n = 0; n < 2; ++n)
          acc[m][n] = __builtin_amdgcn_mfma_f32_16x16x32_bf16(a0[k][m], bv0[k][n], acc[m][n], 0, 0, 0);
    __builtin_amdgcn_s_setprio(0);
    __builtin_amdgcn_sched_barrier(0);

    // Q01: m0-3 x n2-3
    asm volatile("s_waitcnt lgkmcnt(8)" ::: "memory");
    __builtin_amdgcn_sched_barrier(0);
    __builtin_amdgcn_s_setprio(1);
#pragma unroll
    for (int k = 0; k < 2; ++k)
#pragma unroll
      for (int m = 0; m < 4; ++m)
#pragma unroll
        for (int n = 0; n < 2; ++n)
          acc[m][2 + n] = __builtin_amdgcn_mfma_f32_16x16x32_bf16(a0[k][m], bv1[k][n], acc[m][2 + n], 0, 0, 0);
    __builtin_amdgcn_s_setprio(0);
    __builtin_amdgcn_sched_barrier(0);

    // all reads of this buffer done -> barrier, then refill it for tile t+2
    asm volatile("s_waitcnt lgkmcnt(0)" ::: "memory");
    __builtin_amdgcn_sched_barrier(0);
    __builtin_amdgcn_s_barrier();
    __builtin_amdgcn_sched_barrier(0);
    if (t < 22) stage(buf, t + 2);
    __builtin_amdgcn_sched_barrier(0);

    // Q11 + Q10 overlap with the staging loads
    __builtin_amdgcn_s_setprio(1);
#pragma unroll
    for (int k = 0; k < 2; ++k)
#pragma unroll
      for (int m = 0; m < 4; ++m)
#pragma unroll
        for (int n = 0; n < 2; ++n)
          acc[4 + m][2 + n] = __builtin_amdgcn_mfma_f32_16x16x32_bf16(a1[k][m], bv1[k][n], acc[4 + m][2 + n], 0, 0, 0);
#pragma unroll
    for (int k = 0; k < 2; ++k)
#pragma unroll
      for (int m = 0; m < 4; ++m)
#pragma unroll
        for (int n = 0; n < 2; ++n)
          acc[4 + m][n] = __builtin_amdgcn_mfma_f32_16x16x32_bf16(a1[k][m], bv0[k][n], acc[4 + m][n], 0, 0, 0);
    __builtin_amdgcn_s_setprio(0);
    __builtin_amdgcn_sched_barrier(0);
  }

  // epilogue: bias + relu + bf16 store (4 consecutive channels per 8B store)
#pragma unroll
  for (int m = 0; m < 8; ++m) {
    const int o = mbase + wm * 128 + m * 16 + fq * 4;
    const float4 bias = *(const float4*)&bconv[o];
#pragma unroll
    for (int n = 0; n < 4; ++n) {
      const int nl = wn * 64 + n * 16 + fr;
      const long p = (long)prow0 + 1 + nl;
      union { u16 q[4]; uint2 v; } u;
      u.q[0] = f2bf(fmaxf(acc[m][n][0] + bias.x, 0.f));
      u.q[1] = f2bf(fmaxf(acc[m][n][1] + bias.y, 0.f));
      u.q[2] = f2bf(fmaxf(acc[m][n][2] + bias.z, 0.f));
      u.q[3] = f2bf(fmaxf(acc[m][n][3] + bias.w, 0.f));
      *(uint2*)&hout[p * HID_ + o] = u.v;
    }
  }
}

// ---------------- proj_out: out[n][j] = h[n][:] @ W_out[:,j] + b_out (fp32 out) ----------------
__global__ __launch_bounds__(256, 2) void proj_out_gemm(const u16* __restrict__ hin,
                                                        const u16* __restrict__ wob,
                                                        const float* __restrict__ bout,
                                                        float* __restrict__ out) {
  __shared__ __align__(16) u16 Ab[2][128 * 32];   // [n][i]
  __shared__ __align__(16) u16 Bb[2][64 * 32];    // [j][i]
  const int tid = threadIdx.x, wid = tid >> 6, lane = tid & 63;
  const int nt = blockIdx.x;
  const int bb = (nt * 128) / S_, s0v = (nt * 128) % S_;
  const int prow0 = bb * SP_ + s0v + 1;
  const int l4 = lane >> 2, lb = (lane & 3) * 8;
  const int fr = lane & 15, fq = lane >> 4;

  f32x4 acc[2][4];
#pragma unroll
  for (int m = 0; m < 2; ++m)
#pragma unroll
    for (int n = 0; n < 4; ++n) acc[m][n] = {0.f, 0.f, 0.f, 0.f};

  auto stage = [&](int buf, int t) {
    const int i0 = t * 32;
#pragma unroll
    for (int c = 0; c < 2; ++c) {
      const int ch = wid * 2 + c;
      gload16(hin + (long)(prow0 + ch * 16 + l4) * HID_ + i0 + lb, &Ab[buf][ch * 512]);
    }
    gload16(wob + (wid * 16 + l4) * HID_ + i0 + lb, &Bb[buf][wid * 512]);
  };

  stage(0, 0);
  __syncthreads();
  for (int t = 0; t < 16; ++t) {
    const int cur = t & 1;
    if (t < 15) stage(cur ^ 1, t + 1);
    bf16x8 af[2], bfv[4];
#pragma unroll
    for (int m = 0; m < 2; ++m)
      af[m] = *(const bf16x8*)&Ab[cur][(wid * 32 + m * 16 + fr) * 32 + fq * 8];
#pragma unroll
    for (int j = 0; j < 4; ++j)
      bfv[j] = *(const bf16x8*)&Bb[cur][(j * 16 + fr) * 32 + fq * 8];
#pragma unroll
    for (int m = 0; m < 2; ++m)
#pragma unroll
      for (int j = 0; j < 4; ++j)
        acc[m][j] = __builtin_amdgcn_mfma_f32_16x16x32_bf16(af[m], bfv[j], acc[m][j], 0, 0, 0);
    __syncthreads();
  }
  const int n0 = nt * 128;
#pragma unroll
  for (int m = 0; m < 2; ++m) {
    const int nbase = n0 + wid * 32 + m * 16 + fq * 4;
#pragma unroll
    for (int jf = 0; jf < 4; ++jf) {
      const int j = jf * 16 + fr;
      const float bj = bout[j];
#pragma unroll
      for (int r = 0; r < 4; ++r)
        out[(long)(nbase + r) * IN_ + j] = acc[m][jf][r] + bj;
    }
  }
}

extern "C" void kernel_launch(void* const* d_in, const int* in_sizes, int n_in,
                              void* d_out, int out_size, void* d_ws, size_t ws_size,
                              hipStream_t stream) {
  (void)in_sizes; (void)n_in; (void)out_size; (void)ws_size;
  const float* x = (const float*)d_in[0];
  const float* W_in = (const float*)d_in[1];
  const float* b_in = (const float*)d_in[2];
  const float* W_conv = (const float*)d_in[3];
  const float* b_conv = (const float*)d_in[4];
  const float* W_out = (const float*)d_in[5];
  const float* b_out = (const float*)d_in[6];
  float* out = (float*)d_out;
  char* ws = (char*)d_ws;

  const size_t hbytes = (size_t)NP_ * HID_ * sizeof(u16);        // 33,570,816 B
  u16* h0 = (u16*)ws;
  u16* h1 = (u16*)(ws + hbytes);
  u16* wcb = (u16*)(ws + 2 * hbytes);
  u16* wib = (u16*)(ws + 2 * hbytes + (size_t)3 * HID_ * HID_ * 2);
  u16* wob = (u16*)(ws + 2 * hbytes + ((size_t)3 * HID_ * HID_ + IN_ * HID_) * 2);
  u16* xbf = (u16*)(ws + 2 * hbytes + ((size_t)3 * HID_ * HID_ + 2 * IN_ * HID_) * 2);

  // allow 128 KiB dynamic LDS for the conv kernel (host-side attr, not a stream op)
  static int lds_attr_set = 0;
  if (!lds_attr_set) {
    (void)hipFuncSetAttribute((const void*)conv_gemm2,
                              hipFuncAttributeMaxDynamicSharedMemorySize, 131072);
    lds_attr_set = 1;
  }

  setup_kernel<<<2048, 256, 0, stream>>>(x, W_conv, W_in, W_out, wcb, wib, wob, xbf, h0, h1);
  proj_in_gemm<<<dim3(NTOT / 128, HID_ / 128), 256, 0, stream>>>(xbf, wib, b_in, h0);
  const u16* cin = h0;
  u16* cout = h1;
  for (int s = 0; s < NSTEP; ++s) {
    conv_gemm2<<<dim3(NTOT / 256, 2), 512, 131072, stream>>>(cin, cout, wcb, b_conv);
    u16* t = (u16*)cin; cin = cout; cout = t;
  }
  proj_out_gemm<<<NTOT / 128, 256, 0, stream>>>(cin, wob, b_out, out);
}

// Round 3
// 589.195 us; speedup vs baseline: 2.1872x; 2.1872x over previous
//
#include <hip/hip_runtime.h>

#define B_ 8
#define S_ 4096
#define IN_ 64
#define HID_ 512
#define NSTEP 12
#define SP_ (S_ + 2)
#define NP_ (B_ * SP_)
#define NTOT (B_ * S_)

typedef unsigned short u16;
typedef __attribute__((ext_vector_type(8))) short bf16x8;
typedef __attribute__((ext_vector_type(4))) float f32x4;

__device__ __forceinline__ u16 f2bf(float f) {
  unsigned u = __float_as_uint(f);
  u += 0x7fffu + ((u >> 16) & 1u);
  return (u16)(u >> 16);
}

__device__ __forceinline__ void gload16(const void* g, void* l) {
  __builtin_amdgcn_global_load_lds((const __attribute__((address_space(1))) void*)g,
                                   (__attribute__((address_space(3))) void*)l, 16, 0, 0);
}

// ---------------- setup: bf16 conversions + weight transposes + pad-row zeroing ----------------
__global__ void setup_kernel(const float* __restrict__ x, const float* __restrict__ Wc,
                             const float* __restrict__ Wi, const float* __restrict__ Wo,
                             u16* __restrict__ wcb, u16* __restrict__ wib,
                             u16* __restrict__ wob, u16* __restrict__ xbf,
                             u16* __restrict__ h0, u16* __restrict__ h1) {
  const int n_wc = 3 * HID_ * HID_;       // wcb[k][o][i] = Wc[o][i][k]
  const int n_wio = IN_ * HID_;
  const int n_xb = NTOT * IN_;
  const int n_pad = 2 * B_ * 2 * HID_;
  const long total = (long)n_wc + 2 * n_wio + n_xb + n_pad;
  for (long u = (long)blockIdx.x * blockDim.x + threadIdx.x; u < total;
       u += (long)gridDim.x * blockDim.x) {
    long v = u;
    if (v < n_wc) {
      int k = (int)(v / (HID_ * HID_));
      int rem = (int)(v % (HID_ * HID_));
      int o = rem / HID_, i = rem % HID_;
      wcb[v] = f2bf(Wc[((long)o * HID_ + i) * 3 + k]);
    } else if ((v -= n_wc) < n_wio) {      // wib[i][j] = Wi[j][i]
      int i = (int)(v / IN_), j = (int)(v % IN_);
      wib[v] = f2bf(Wi[j * HID_ + i]);
    } else if ((v -= n_wio) < n_wio) {     // wob[j][i] = Wo[i][j]
      int j = (int)(v / HID_), i = (int)(v % HID_);
      wob[v] = f2bf(Wo[i * IN_ + j]);
    } else if ((v -= n_wio) < n_xb) {
      xbf[v] = f2bf(x[v]);
    } else {
      v -= n_xb;                           // zero pad rows (s=-1 and s=S per batch, both buffers)
      int buf = (int)(v / (B_ * 2 * HID_));
      int r = (int)(v % (B_ * 2 * HID_));
      int b = r / (2 * HID_);
      int q = r % (2 * HID_);
      int side = q / HID_, i = q % HID_;
      long p = (long)b * SP_ + (side ? (S_ + 1) : 0);
      (buf ? h1 : h0)[p * HID_ + i] = 0;
    }
  }
}

// ---------------- proj_in: h0[n][i] = x[n][:] @ W_in[:,i] + b_in  (bf16 MFMA, K=64) ----------------
__global__ __launch_bounds__(256, 2) void proj_in_gemm(const u16* __restrict__ xb,
                                                       const u16* __restrict__ wib,
                                                       const float* __restrict__ bin,
                                                       u16* __restrict__ hout) {
  __shared__ __align__(16) u16 Ab[128 * 64];
  __shared__ __align__(16) u16 Bb[128 * 64];
  const int tid = threadIdx.x, wid = tid >> 6, lane = tid & 63;
  const int nt = blockIdx.x, mt = blockIdx.y;
  const int wr = wid >> 1, wcn = wid & 1, fr = lane & 15, fq = lane >> 4;
#pragma unroll
  for (int c = 0; c < 4; ++c) {
    const int ch = wid * 4 + c;
    const int row = ch * 8 + (lane >> 3), cb = (lane & 7) * 8;
    gload16(wib + (mt * 128 + row) * 64 + cb, &Ab[ch * 512]);
    gload16(xb + ((long)nt * 128 + row) * 64 + cb, &Bb[ch * 512]);
  }
  f32x4 acc[4][4];
#pragma unroll
  for (int m = 0; m < 4; ++m)
#pragma unroll
    for (int n = 0; n < 4; ++n) acc[m][n] = {0.f, 0.f, 0.f, 0.f};
  __syncthreads();
#pragma unroll
  for (int t = 0; t < 2; ++t) {
    const int j0 = t * 32;
    bf16x8 af[4], bfv[4];
#pragma unroll
    for (int m = 0; m < 4; ++m)
      af[m] = *(const bf16x8*)&Ab[(wr * 64 + m * 16 + fr) * 64 + j0 + fq * 8];
#pragma unroll
    for (int n = 0; n < 4; ++n)
      bfv[n] = *(const bf16x8*)&Bb[(wcn * 64 + n * 16 + fr) * 64 + j0 + fq * 8];
#pragma unroll
    for (int m = 0; m < 4; ++m)
#pragma unroll
      for (int n = 0; n < 4; ++n)
        acc[m][n] = __builtin_amdgcn_mfma_f32_16x16x32_bf16(af[m], bfv[n], acc[m][n], 0, 0, 0);
  }
  const int n0 = nt * 128;
  const int bb = n0 / S_, s0v = n0 % S_;
  const int prow = bb * SP_ + s0v + 1;
#pragma unroll
  for (int m = 0; m < 4; ++m) {
    const int i = mt * 128 + wr * 64 + m * 16 + fq * 4;
    const float4 bias = *(const float4*)&bin[i];
#pragma unroll
    for (int n = 0; n < 4; ++n) {
      const int nl = wcn * 64 + n * 16 + fr;
      const long p = prow + nl;
      union { u16 q[4]; uint2 v; } u;
      u.q[0] = f2bf(acc[m][n][0] + bias.x);
      u.q[1] = f2bf(acc[m][n][1] + bias.y);
      u.q[2] = f2bf(acc[m][n][2] + bias.z);
      u.q[3] = f2bf(acc[m][n][3] + bias.w);
      *(uint2*)&hout[p * HID_ + i] = u.v;
    }
  }
}

// ---------------- conv step: 256x256 tile, BK=32, 4 LDS buffers, depth-3 prefetch ----------------
// C[o,n] = relu(sum_{k,i} W[o,i,k] h[i,n+k-1] + b), bf16 in/out.
// LDS: 4 bufs x (A 256x32 + B 256x32) bf16 = 128 KiB. Rows are 64 B; swizzle
// byte ^= ((row>>1)&3)<<4 (involution; row-axis bank aliasing 8-way -> 2-way = free).
// Schedule per K-tile: vmcnt(8), barrier, {reads g1 | stage t+3 | reads g2},
// lgkmcnt(4) -> 16 MFMA, lgkmcnt(0) -> 16 MFMA. One barrier/tile, never vmcnt(0).
__global__ __launch_bounds__(512, 2) void conv_gemm3(const u16* __restrict__ hin,
                                                     u16* __restrict__ hout,
                                                     const u16* __restrict__ wcb,
                                                     const float* __restrict__ bconv) {
  extern __shared__ __align__(16) u16 smem[];
  const int tid = threadIdx.x;
  const int w = tid >> 6, lane = tid & 63;
  const int wm = w >> 2, wn = w & 3;          // 2 x 4 wave grid; per-wave C = 128 x 64
  const int fr = lane & 15, fq = lane >> 4;
  const int mbase = blockIdx.y * 256;
  const int n0 = blockIdx.x * 256;
  const int bb = n0 / S_, s0 = n0 % S_;
  const int prow0 = bb * SP_ + s0;            // tap-k B rows start at prow0+k

  // staging geometry: linear LDS byte d = c*8192 + tid*16; logical byte
  // l = d ^ (((d>>7)&3)<<4) -> pre-swizzled global source (m173 pattern).
  const int tl = (tid * 16) ^ (((tid >> 3) & 3) << 4);
  const int srow = tl >> 6;                   // 0..127 (chunk-local row)
  const int scol = (tl & 63) >> 1;            // element col (multiple of 8)
  const int wdst = w * 1024;                  // wave-uniform LDS byte base within chunk

  auto stage = [&](int dbuf, int u) {
    const int kk = u % 3;                     // tap (tap-inner: L2-hot re-reads)
    const int i0 = (u / 3) * 32;              // input-channel slice
    char* base = (char*)smem + (size_t)dbuf * 32768;
    const u16* ga = wcb + (size_t)kk * (HID_ * HID_) + (size_t)(mbase + srow) * HID_ + i0 + scol;
    const u16* gb = hin + (size_t)(prow0 + kk + srow) * HID_ + i0 + scol;
    gload16(ga, base + wdst);
    gload16(ga + 128 * HID_, base + 8192 + wdst);
    gload16(gb, base + 16384 + wdst);
    gload16(gb + 128 * HID_, base + 24576 + wdst);
  };

  f32x4 acc[8][4];
#pragma unroll
  for (int m = 0; m < 8; ++m)
#pragma unroll
    for (int n = 0; n < 4; ++n) acc[m][n] = {0.f, 0.f, 0.f, 0.f};

  stage(0, 0);
  stage(1, 1);
  stage(2, 2);

  // ds_read offsets: byte = row*64 + fq*16, swizzle XOR = ((fr>>1)&3)<<4
  // (wm*128, wn*64, m*16, n*16 are all ==0 mod 8 rows -> swz depends on fr only).
  const int swzb = ((fr >> 1) & 3) << 4;
  const int aoffs = (((wm * 128 + fr) * 64 + fq * 16)) ^ swzb;
  const int boffs = (((wn * 64 + fr) * 64 + fq * 16)) ^ swzb;

#pragma unroll 12
  for (int t = 0; t < 48; ++t) {
    const int buf = t & 3;
    const char* A = (const char*)smem + (size_t)buf * 32768;
    const char* Bv = A + 16384;

    // this wave's tile-t loads done (<=8 outstanding); barrier proves ALL waves' are
    asm volatile("s_waitcnt vmcnt(8)" ::: "memory");
    __builtin_amdgcn_sched_barrier(0);
    __builtin_amdgcn_s_barrier();
    __builtin_amdgcn_sched_barrier(0);

    bf16x8 af[8], bfv[4];
    // group 1: A m0-3 + B n0-3 (8 ds_reads)
#pragma unroll
    for (int m = 0; m < 4; ++m)
      af[m] = *(const bf16x8*)(A + aoffs + m * 1024);
#pragma unroll
    for (int n = 0; n < 4; ++n)
      bfv[n] = *(const bf16x8*)(Bv + boffs + n * 1024);
    __builtin_amdgcn_sched_barrier(0);
    // prefetch K-tile t+3 (depth 3 ~= 3*1242cy issue-to-wait; dummy re-stage past end)
    {
      int u = t + 3;
      if (u > 47) u = 47;
      stage((t + 3) & 3, u);
    }
    __builtin_amdgcn_sched_barrier(0);
    // group 2: A m4-7 (4 ds_reads)
#pragma unroll
    for (int m = 4; m < 8; ++m)
      af[m] = *(const bf16x8*)(A + aoffs + m * 1024);
    __builtin_amdgcn_sched_barrier(0);

    // phase 0: group-1 frags ready (group 2 may still fly)
    asm volatile("s_waitcnt lgkmcnt(4)" ::: "memory");
    __builtin_amdgcn_sched_barrier(0);
    __builtin_amdgcn_s_setprio(1);
#pragma unroll
    for (int m = 0; m < 4; ++m)
#pragma unroll
      for (int n = 0; n < 4; ++n)
        acc[m][n] = __builtin_amdgcn_mfma_f32_16x16x32_bf16(af[m], bfv[n], acc[m][n], 0, 0, 0);
    __builtin_amdgcn_s_setprio(0);
    __builtin_amdgcn_sched_barrier(0);

    // phase 1: rest of A
    asm volatile("s_waitcnt lgkmcnt(0)" ::: "memory");
    __builtin_amdgcn_sched_barrier(0);
    __builtin_amdgcn_s_setprio(1);
#pragma unroll
    for (int m = 4; m < 8; ++m)
#pragma unroll
      for (int n = 0; n < 4; ++n)
        acc[m][n] = __builtin_amdgcn_mfma_f32_16x16x32_bf16(af[m], bfv[n], acc[m][n], 0, 0, 0);
    __builtin_amdgcn_s_setprio(0);
    __builtin_amdgcn_sched_barrier(0);
  }

  // epilogue: bias + relu + bf16 store (4 consecutive channels per 8B store)
#pragma unroll
  for (int m = 0; m < 8; ++m) {
    const int o = mbase + wm * 128 + m * 16 + fq * 4;
    const float4 bias = *(const float4*)&bconv[o];
#pragma unroll
    for (int n = 0; n < 4; ++n) {
      const int nl = wn * 64 + n * 16 + fr;
      const long p = (long)prow0 + 1 + nl;
      union { u16 q[4]; uint2 v; } u;
      u.q[0] = f2bf(fmaxf(acc[m][n][0] + bias.x, 0.f));
      u.q[1] = f2bf(fmaxf(acc[m][n][1] + bias.y, 0.f));
      u.q[2] = f2bf(fmaxf(acc[m][n][2] + bias.z, 0.f));
      u.q[3] = f2bf(fmaxf(acc[m][n][3] + bias.w, 0.f));
      *(uint2*)&hout[p * HID_ + o] = u.v;
    }
  }
}

// ---------------- proj_out: out[n][j] = h[n][:] @ W_out[:,j] + b_out (fp32 out) ----------------
__global__ __launch_bounds__(256, 2) void proj_out_gemm(const u16* __restrict__ hin,
                                                        const u16* __restrict__ wob,
                                                        const float* __restrict__ bout,
                                                        float* __restrict__ out) {
  __shared__ __align__(16) u16 Ab[2][128 * 32];   // [n][i]
  __shared__ __align__(16) u16 Bb[2][64 * 32];    // [j][i]
  const int tid = threadIdx.x, wid = tid >> 6, lane = tid & 63;
  const int nt = blockIdx.x;
  const int bb = (nt * 128) / S_, s0v = (nt * 128) % S_;
  const int prow0 = bb * SP_ + s0v + 1;
  const int l4 = lane >> 2, lb = (lane & 3) * 8;
  const int fr = lane & 15, fq = lane >> 4;

  f32x4 acc[2][4];
#pragma unroll
  for (int m = 0; m < 2; ++m)
#pragma unroll
    for (int n = 0; n < 4; ++n) acc[m][n] = {0.f, 0.f, 0.f, 0.f};

  auto stage = [&](int buf, int t) {
    const int i0 = t * 32;
#pragma unroll
    for (int c = 0; c < 2; ++c) {
      const int ch = wid * 2 + c;
      gload16(hin + (long)(prow0 + ch * 16 + l4) * HID_ + i0 + lb, &Ab[buf][ch * 512]);
    }
    gload16(wob + (wid * 16 + l4) * HID_ + i0 + lb, &Bb[buf][wid * 512]);
  };

  stage(0, 0);
  __syncthreads();
  for (int t = 0; t < 16; ++t) {
    const int cur = t & 1;
    if (t < 15) stage(cur ^ 1, t + 1);
    bf16x8 af[2], bfv[4];
#pragma unroll
    for (int m = 0; m < 2; ++m)
      af[m] = *(const bf16x8*)&Ab[cur][(wid * 32 + m * 16 + fr) * 32 + fq * 8];
#pragma unroll
    for (int j = 0; j < 4; ++j)
      bfv[j] = *(const bf16x8*)&Bb[cur][(j * 16 + fr) * 32 + fq * 8];
#pragma unroll
    for (int m = 0; m < 2; ++m)
#pragma unroll
      for (int j = 0; j < 4; ++j)
        acc[m][j] = __builtin_amdgcn_mfma_f32_16x16x32_bf16(af[m], bfv[j], acc[m][j], 0, 0, 0);
    __syncthreads();
  }
  const int n0 = nt * 128;
#pragma unroll
  for (int m = 0; m < 2; ++m) {
    const int nbase = n0 + wid * 32 + m * 16 + fq * 4;
#pragma unroll
    for (int jf = 0; jf < 4; ++jf) {
      const int j = jf * 16 + fr;
      const float bj = bout[j];
#pragma unroll
      for (int r = 0; r < 4; ++r)
        out[(long)(nbase + r) * IN_ + j] = acc[m][jf][r] + bj;
    }
  }
}

extern "C" void kernel_launch(void* const* d_in, const int* in_sizes, int n_in,
                              void* d_out, int out_size, void* d_ws, size_t ws_size,
                              hipStream_t stream) {
  (void)in_sizes; (void)n_in; (void)out_size; (void)ws_size;
  const float* x = (const float*)d_in[0];
  const float* W_in = (const float*)d_in[1];
  const float* b_in = (const float*)d_in[2];
  const float* W_conv = (const float*)d_in[3];
  const float* b_conv = (const float*)d_in[4];
  const float* W_out = (const float*)d_in[5];
  const float* b_out = (const float*)d_in[6];
  float* out = (float*)d_out;
  char* ws = (char*)d_ws;

  const size_t hbytes = (size_t)NP_ * HID_ * sizeof(u16);        // 33,570,816 B
  u16* h0 = (u16*)ws;
  u16* h1 = (u16*)(ws + hbytes);
  u16* wcb = (u16*)(ws + 2 * hbytes);
  u16* wib = (u16*)(ws + 2 * hbytes + (size_t)3 * HID_ * HID_ * 2);
  u16* wob = (u16*)(ws + 2 * hbytes + ((size_t)3 * HID_ * HID_ + IN_ * HID_) * 2);
  u16* xbf = (u16*)(ws + 2 * hbytes + ((size_t)3 * HID_ * HID_ + 2 * IN_ * HID_) * 2);

  // allow 128 KiB dynamic LDS for the conv kernel (host-side attr, idempotent)
  static int lds_attr_set = 0;
  if (!lds_attr_set) {
    (void)hipFuncSetAttribute((const void*)conv_gemm3,
                              hipFuncAttributeMaxDynamicSharedMemorySize, 131072);
    lds_attr_set = 1;
  }

  setup_kernel<<<2048, 256, 0, stream>>>(x, W_conv, W_in, W_out, wcb, wib, wob, xbf, h0, h1);
  proj_in_gemm<<<dim3(NTOT / 128, HID_ / 128), 256, 0, stream>>>(xbf, wib, b_in, h0);
  const u16* cin = h0;
  u16* cout = h1;
  for (int s = 0; s < NSTEP; ++s) {
    conv_gemm3<<<dim3(NTOT / 256, 2), 512, 131072, stream>>>(cin, cout, wcb, b_conv);
    u16* t = (u16*)cin; cin = cout; cout = t;
  }
  proj_out_gemm<<<NTOT / 128, 256, 0, stream>>>(cin, wob, b_out, out);
}

// Round 4
// 582.890 us; speedup vs baseline: 2.2109x; 1.0108x over previous
//
#include <hip/hip_runtime.h>

#define B_ 8
#define S_ 4096
#define IN_ 64
#define HID_ 512
#define NSTEP 12
#define SP_ (S_ + 2)
#define NP_ (B_ * SP_)
#define NTOT (B_ * S_)

typedef unsigned short u16;
typedef __attribute__((ext_vector_type(8))) short bf16x8;
typedef __attribute__((ext_vector_type(4))) float f32x4;

__device__ __forceinline__ u16 f2bf(float f) {
  unsigned u = __float_as_uint(f);
  u += 0x7fffu + ((u >> 16) & 1u);
  return (u16)(u >> 16);
}

__device__ __forceinline__ void gload16(const void* g, void* l) {
  __builtin_amdgcn_global_load_lds((const __attribute__((address_space(1))) void*)g,
                                   (__attribute__((address_space(3))) void*)l, 16, 0, 0);
}

// ---------------- setup: bf16 conversions + weight transposes + pad-row zeroing ----------------
__global__ void setup_kernel(const float* __restrict__ x, const float* __restrict__ Wc,
                             const float* __restrict__ Wi, const float* __restrict__ Wo,
                             u16* __restrict__ wcb, u16* __restrict__ wib,
                             u16* __restrict__ wob, u16* __restrict__ xbf,
                             u16* __restrict__ h0, u16* __restrict__ h1) {
  const int n_wc = 3 * HID_ * HID_;       // wcb[k][o][i] = Wc[o][i][k]
  const int n_wio = IN_ * HID_;
  const int n_xb = NTOT * IN_;
  const int n_pad = 2 * B_ * 2 * HID_;
  const long total = (long)n_wc + 2 * n_wio + n_xb + n_pad;
  for (long u = (long)blockIdx.x * blockDim.x + threadIdx.x; u < total;
       u += (long)gridDim.x * blockDim.x) {
    long v = u;
    if (v < n_wc) {
      int k = (int)(v / (HID_ * HID_));
      int rem = (int)(v % (HID_ * HID_));
      int o = rem / HID_, i = rem % HID_;
      wcb[v] = f2bf(Wc[((long)o * HID_ + i) * 3 + k]);
    } else if ((v -= n_wc) < n_wio) {      // wib[i][j] = Wi[j][i]
      int i = (int)(v / IN_), j = (int)(v % IN_);
      wib[v] = f2bf(Wi[j * HID_ + i]);
    } else if ((v -= n_wio) < n_wio) {     // wob[j][i] = Wo[i][j]
      int j = (int)(v / HID_), i = (int)(v % HID_);
      wob[v] = f2bf(Wo[i * IN_ + j]);
    } else if ((v -= n_wio) < n_xb) {
      xbf[v] = f2bf(x[v]);
    } else {
      v -= n_xb;                           // zero pad rows (s=-1 and s=S per batch, both buffers)
      int buf = (int)(v / (B_ * 2 * HID_));
      int r = (int)(v % (B_ * 2 * HID_));
      int b = r / (2 * HID_);
      int q = r % (2 * HID_);
      int side = q / HID_, i = q % HID_;
      long p = (long)b * SP_ + (side ? (S_ + 1) : 0);
      (buf ? h1 : h0)[p * HID_ + i] = 0;
    }
  }
}

// ---------------- proj_in: h0[n][i] = x[n][:] @ W_in[:,i] + b_in  (bf16 MFMA, K=64) ----------------
__global__ __launch_bounds__(256, 2) void proj_in_gemm(const u16* __restrict__ xb,
                                                       const u16* __restrict__ wib,
                                                       const float* __restrict__ bin,
                                                       u16* __restrict__ hout) {
  __shared__ __align__(16) u16 Ab[128 * 64];
  __shared__ __align__(16) u16 Bb[128 * 64];
  const int tid = threadIdx.x, wid = tid >> 6, lane = tid & 63;
  const int nt = blockIdx.x, mt = blockIdx.y;
  const int wr = wid >> 1, wcn = wid & 1, fr = lane & 15, fq = lane >> 4;
#pragma unroll
  for (int c = 0; c < 4; ++c) {
    const int ch = wid * 4 + c;
    const int row = ch * 8 + (lane >> 3), cb = (lane & 7) * 8;
    gload16(wib + (mt * 128 + row) * 64 + cb, &Ab[ch * 512]);
    gload16(xb + ((long)nt * 128 + row) * 64 + cb, &Bb[ch * 512]);
  }
  f32x4 acc[4][4];
#pragma unroll
  for (int m = 0; m < 4; ++m)
#pragma unroll
    for (int n = 0; n < 4; ++n) acc[m][n] = {0.f, 0.f, 0.f, 0.f};
  __syncthreads();
#pragma unroll
  for (int t = 0; t < 2; ++t) {
    const int j0 = t * 32;
    bf16x8 af[4], bfv[4];
#pragma unroll
    for (int m = 0; m < 4; ++m)
      af[m] = *(const bf16x8*)&Ab[(wr * 64 + m * 16 + fr) * 64 + j0 + fq * 8];
#pragma unroll
    for (int n = 0; n < 4; ++n)
      bfv[n] = *(const bf16x8*)&Bb[(wcn * 64 + n * 16 + fr) * 64 + j0 + fq * 8];
#pragma unroll
    for (int m = 0; m < 4; ++m)
#pragma unroll
      for (int n = 0; n < 4; ++n)
        acc[m][n] = __builtin_amdgcn_mfma_f32_16x16x32_bf16(af[m], bfv[n], acc[m][n], 0, 0, 0);
  }
  const int n0 = nt * 128;
  const int bb = n0 / S_, s0v = n0 % S_;
  const int prow = bb * SP_ + s0v + 1;
#pragma unroll
  for (int m = 0; m < 4; ++m) {
    const int i = mt * 128 + wr * 64 + m * 16 + fq * 4;
    const float4 bias = *(const float4*)&bin[i];
#pragma unroll
    for (int n = 0; n < 4; ++n) {
      const int nl = wcn * 64 + n * 16 + fr;
      const long p = prow + nl;
      union { u16 q[4]; uint2 v; } u;
      u.q[0] = f2bf(acc[m][n][0] + bias.x);
      u.q[1] = f2bf(acc[m][n][1] + bias.y);
      u.q[2] = f2bf(acc[m][n][2] + bias.z);
      u.q[3] = f2bf(acc[m][n][3] + bias.w);
      *(uint2*)&hout[p * HID_ + i] = u.v;
    }
  }
}

// ---------------- conv step: 256x256 tile, BK=64, 2 dbuf, 8-phase counted-vmcnt ----------------
// C[o,n] = relu(sum_{k,i} W[o,i,k] h[i,n+k-1] + b), bf16 in/out.
// K-units u = 0..23: tap kk=u%3, i-slice i0=(u/3)*64 (tap-inner: B re-reads L2-hot).
// LDS (bytes): A d0 [0,32K), A d1 [32K,64K), B d0 [64K,96K), B d1 [96K,128K).
// Logical tiles [256 rows][64 cols] bf16, 128-B rows; swizzle byte ^= ((row&7)<<4) on
// both the staged global source and the ds_read addr (linear gload_lds dest).
// Regions: SA0 = A rows {0-63,128-191}, SA1 = {64-127,192-255}, SB0 = B rows 0-127,
// SB1 = 128-255. Phase schedule per iter (tiles u0=2j->d0, u1=2j+1->d1):
//  ph1*: rd A0.mh0.k0 + B0.k0 | st SB0(u1)   ph5*: rd A1.mh0.k0 + B1.k0 | st SB0(u0+2)
//  ph2*: rd A0.mh1.k0         | st SB1(u1)   ph6*: rd A1.mh1.k0         | st SB1(u0+2)
//  ph3 : rd A0.mh0.k1 + B0.k1 | st SA1(u1)   ph7 : rd A1.mh0.k1 + B1.k1 | st SA1(u0+2)
//  ph4 : rd A0.mh1.k1         | st SA0(u0+2) ph8 : rd A1.mh1.k1         | st SA0(u1+2)
// (* = vmcnt(4)+barrier gate; every phase ends lgkm(0) -> 16 MFMA -> barrier).
// Each region's re-stage slot is >=1 phase-end barrier after its last reader; each
// gate drains exactly the 1-3 oldest slots the next reads need (FIFO-verified).
#define GATE4()                                        \
  asm volatile("s_waitcnt vmcnt(4)" ::: "memory");     \
  __builtin_amdgcn_sched_barrier(0);                   \
  __builtin_amdgcn_s_barrier();                        \
  __builtin_amdgcn_sched_barrier(0);

#define ENDPH()                                        \
  __builtin_amdgcn_sched_barrier(0);                   \
  __builtin_amdgcn_s_barrier();                        \
  __builtin_amdgcn_sched_barrier(0);

#define MFMA16(MB)                                     \
  asm volatile("s_waitcnt lgkmcnt(0)" ::: "memory");   \
  __builtin_amdgcn_sched_barrier(0);                   \
  __builtin_amdgcn_s_setprio(1);                       \
  _Pragma("unroll")                                    \
  for (int mf = 0; mf < 4; ++mf)                       \
    _Pragma("unroll")                                  \
    for (int nf = 0; nf < 4; ++nf)                     \
      acc[(MB) + mf][nf] = __builtin_amdgcn_mfma_f32_16x16x32_bf16(af[mf], bf[nf], acc[(MB) + mf][nf], 0, 0, 0); \
  __builtin_amdgcn_s_setprio(0);                       \
  __builtin_amdgcn_sched_barrier(0);

#define LDA4(BASE, MB, KH)                             \
  _Pragma("unroll")                                    \
  for (int mf = 0; mf < 4; ++mf)                       \
    af[mf] = *(const bf16x8*)((BASE) + (((abase + (KH) * 64) ^ swz) + ((MB) + mf) * 2048));

#define LDB4(BASE, KH)                                 \
  _Pragma("unroll")                                    \
  for (int nf = 0; nf < 4; ++nf)                       \
    bf[nf] = *(const bf16x8*)((BASE) + (((bbase + (KH) * 64) ^ swz) + nf * 2048));

__global__ __launch_bounds__(512, 2) void conv_gemm4(const u16* __restrict__ hin,
                                                     u16* __restrict__ hout,
                                                     const u16* __restrict__ wcb,
                                                     const float* __restrict__ bconv) {
  extern __shared__ __align__(16) u16 smem[];
  const int tid = threadIdx.x;
  const int w = tid >> 6, lane = tid & 63;
  const int wm = w >> 2, wn = w & 3;          // 2 x 4 wave grid; per-wave C = 128 x 64
  const int fr = lane & 15, fq = lane >> 4;
  const int mbase = blockIdx.y * 256;
  const int n0 = blockIdx.x * 256;
  const int bb = n0 / S_, s0 = n0 % S_;
  const int prow0 = bb * SP_ + s0;            // tap-k B rows start at prow0+k

  // staging per-thread coords: linear LDS byte within an 8KB strip = tid*16;
  // logical row = tid>>3, logical col byte = (tid&7)*16 ^ ((row&7)<<4) (inverse swizzle).
  const int srow = tid >> 3;                  // 0..63
  const int scol = (((tid & 7) * 16) ^ (((tid >> 3) & 7) << 4)) >> 1;
  const int wdst = w * 1024;

  // stage one region (2 x gload16, 16KB total) of K-tile u into dbuf d.
  // r: 0=SA0, 1=SB0, 2=SB1, 3=SA1
  auto stage = [&](int d, int u, int r) {
    if (u > 23) u = 23;                       // tail clamp: dummy re-stage keeps vmcnt uniform
    const int kk = u % 3;
    const int i0 = (u / 3) * 64;
    if (r == 0 || r == 3) {
      const int rb = (r == 0) ? 0 : 64;
      char* dst = (char*)smem + d * 32768 + rb * 128;
      const u16* g = wcb + (size_t)kk * (HID_ * HID_) + (size_t)(mbase + rb + srow) * HID_ + i0 + scol;
      gload16(g, dst + wdst);
      gload16(g + 128 * HID_, dst + 16384 + wdst);
    } else {
      const int rb = (r == 1) ? 0 : 128;
      char* dst = (char*)smem + 65536 + d * 32768 + rb * 128;
      const u16* g = hin + (size_t)(prow0 + kk + rb + srow) * HID_ + i0 + scol;
      gload16(g, dst + wdst);
      gload16(g + 64 * HID_, dst + 8192 + wdst);
    }
  };

  f32x4 acc[8][4];
#pragma unroll
  for (int m = 0; m < 8; ++m)
#pragma unroll
    for (int n = 0; n < 4; ++n) acc[m][n] = {0.f, 0.f, 0.f, 0.f};

  // prologue: tile 0 complete (d0) + SA0 of tile 1 (d1)  -> 10 loads in flight
  stage(0, 0, 0); stage(0, 0, 1); stage(0, 0, 2); stage(0, 0, 3);
  stage(1, 1, 0);

  // ds_read constants: byte = row*128 + kh*64 + fq*16, swizzled by ((row&7)<<4) = ((fr&7)<<4)
  const int swz = (fr & 7) << 4;
  const int abase = (wm * 128 + fr) * 128 + fq * 16;
  const int bbase = (wn * 64 + fr) * 128 + fq * 16;
  const char* A0 = (const char*)smem;
  const char* A1 = (const char*)smem + 32768;
  const char* B0 = (const char*)smem + 65536;
  const char* B1 = (const char*)smem + 98304;

  for (int j = 0; j < 12; ++j) {
    const int u1 = 2 * j + 1, u2 = 2 * j + 2, u3 = 2 * j + 3;
    bf16x8 af[4], bf[4];

    // ph1: d0 mh0 k0 (gated: needs SA0d0, SB0d0, SB1d0)
    GATE4();
    LDA4(A0, 0, 0); LDB4(B0, 0);
    stage(1, u1, 1);
    MFMA16(0);
    ENDPH();

    // ph2: d0 mh1 k0 (gated: needs SA1d0)
    GATE4();
    LDA4(A0, 4, 0);
    stage(1, u1, 2);
    MFMA16(4);
    ENDPH();

    // ph3: d0 mh0 k1
    LDA4(A0, 0, 1); LDB4(B0, 1);
    stage(1, u1, 3);
    MFMA16(0);
    ENDPH();

    // ph4: d0 mh1 k1   (SA0 d0 freed at ph3-end -> restage)
    LDA4(A0, 4, 1);
    stage(0, u2, 0);
    MFMA16(4);
    ENDPH();

    // ph5: d1 mh0 k0 (gated: needs SA0d1, SB0d1, SB1d1)
    GATE4();
    LDA4(A1, 0, 0); LDB4(B1, 0);
    stage(0, u2, 1);
    MFMA16(0);
    ENDPH();

    // ph6: d1 mh1 k0 (gated: needs SA1d1)
    GATE4();
    LDA4(A1, 4, 0);
    stage(0, u2, 2);
    MFMA16(4);
    ENDPH();

    // ph7: d1 mh0 k1
    LDA4(A1, 0, 1); LDB4(B1, 1);
    stage(0, u2, 3);
    MFMA16(0);
    ENDPH();

    // ph8: d1 mh1 k1   (SA0 d1 freed at ph7-end -> restage for tile u3)
    LDA4(A1, 4, 1);
    stage(1, u3, 0);
    MFMA16(4);
    ENDPH();
  }

  // epilogue: bias + relu + bf16 store (4 consecutive channels per 8B store)
#pragma unroll
  for (int m = 0; m < 8; ++m) {
    const int o = mbase + wm * 128 + m * 16 + fq * 4;
    const float4 bias = *(const float4*)&bconv[o];
#pragma unroll
    for (int n = 0; n < 4; ++n) {
      const int nl = wn * 64 + n * 16 + fr;
      const long p = (long)prow0 + 1 + nl;
      union { u16 q[4]; uint2 v; } u;
      u.q[0] = f2bf(fmaxf(acc[m][n][0] + bias.x, 0.f));
      u.q[1] = f2bf(fmaxf(acc[m][n][1] + bias.y, 0.f));
      u.q[2] = f2bf(fmaxf(acc[m][n][2] + bias.z, 0.f));
      u.q[3] = f2bf(fmaxf(acc[m][n][3] + bias.w, 0.f));
      *(uint2*)&hout[p * HID_ + o] = u.v;
    }
  }
}

// ---------------- proj_out: out[n][j] = h[n][:] @ W_out[:,j] + b_out (fp32 out) ----------------
__global__ __launch_bounds__(256, 2) void proj_out_gemm(const u16* __restrict__ hin,
                                                        const u16* __restrict__ wob,
                                                        const float* __restrict__ bout,
                                                        float* __restrict__ out) {
  __shared__ __align__(16) u16 Ab[2][128 * 32];   // [n][i]
  __shared__ __align__(16) u16 Bb[2][64 * 32];    // [j][i]
  const int tid = threadIdx.x, wid = tid >> 6, lane = tid & 63;
  const int nt = blockIdx.x;
  const int bb = (nt * 128) / S_, s0v = (nt * 128) % S_;
  const int prow0 = bb * SP_ + s0v + 1;
  const int l4 = lane >> 2, lb = (lane & 3) * 8;
  const int fr = lane & 15, fq = lane >> 4;

  f32x4 acc[2][4];
#pragma unroll
  for (int m = 0; m < 2; ++m)
#pragma unroll
    for (int n = 0; n < 4; ++n) acc[m][n] = {0.f, 0.f, 0.f, 0.f};

  auto stage = [&](int buf, int t) {
    const int i0 = t * 32;
#pragma unroll
    for (int c = 0; c < 2; ++c) {
      const int ch = wid * 2 + c;
      gload16(hin + (long)(prow0 + ch * 16 + l4) * HID_ + i0 + lb, &Ab[buf][ch * 512]);
    }
    gload16(wob + (wid * 16 + l4) * HID_ + i0 + lb, &Bb[buf][wid * 512]);
  };

  stage(0, 0);
  __syncthreads();
  for (int t = 0; t < 16; ++t) {
    const int cur = t & 1;
    if (t < 15) stage(cur ^ 1, t + 1);
    bf16x8 af[2], bfv[4];
#pragma unroll
    for (int m = 0; m < 2; ++m)
      af[m] = *(const bf16x8*)&Ab[cur][(wid * 32 + m * 16 + fr) * 32 + fq * 8];
#pragma unroll
    for (int j = 0; j < 4; ++j)
      bfv[j] = *(const bf16x8*)&Bb[cur][(j * 16 + fr) * 32 + fq * 8];
#pragma unroll
    for (int m = 0; m < 2; ++m)
#pragma unroll
      for (int j = 0; j < 4; ++j)
        acc[m][j] = __builtin_amdgcn_mfma_f32_16x16x32_bf16(af[m], bfv[j], acc[m][j], 0, 0, 0);
    __syncthreads();
  }
  const int n0 = nt * 128;
#pragma unroll
  for (int m = 0; m < 2; ++m) {
    const int nbase = n0 + wid * 32 + m * 16 + fq * 4;
#pragma unroll
    for (int jf = 0; jf < 4; ++jf) {
      const int j = jf * 16 + fr;
      const float bj = bout[j];
#pragma unroll
      for (int r = 0; r < 4; ++r)
        out[(long)(nbase + r) * IN_ + j] = acc[m][jf][r] + bj;
    }
  }
}

extern "C" void kernel_launch(void* const* d_in, const int* in_sizes, int n_in,
                              void* d_out, int out_size, void* d_ws, size_t ws_size,
                              hipStream_t stream) {
  (void)in_sizes; (void)n_in; (void)out_size; (void)ws_size;
  const float* x = (const float*)d_in[0];
  const float* W_in = (const float*)d_in[1];
  const float* b_in = (const float*)d_in[2];
  const float* W_conv = (const float*)d_in[3];
  const float* b_conv = (const float*)d_in[4];
  const float* W_out = (const float*)d_in[5];
  const float* b_out = (const float*)d_in[6];
  float* out = (float*)d_out;
  char* ws = (char*)d_ws;

  const size_t hbytes = (size_t)NP_ * HID_ * sizeof(u16);        // 33,570,816 B
  u16* h0 = (u16*)ws;
  u16* h1 = (u16*)(ws + hbytes);
  u16* wcb = (u16*)(ws + 2 * hbytes);
  u16* wib = (u16*)(ws + 2 * hbytes + (size_t)3 * HID_ * HID_ * 2);
  u16* wob = (u16*)(ws + 2 * hbytes + ((size_t)3 * HID_ * HID_ + IN_ * HID_) * 2);
  u16* xbf = (u16*)(ws + 2 * hbytes + ((size_t)3 * HID_ * HID_ + 2 * IN_ * HID_) * 2);

  // allow 128 KiB dynamic LDS for the conv kernel (host-side attr, idempotent)
  static int lds_attr_set = 0;
  if (!lds_attr_set) {
    (void)hipFuncSetAttribute((const void*)conv_gemm4,
                              hipFuncAttributeMaxDynamicSharedMemorySize, 131072);
    lds_attr_set = 1;
  }

  setup_kernel<<<2048, 256, 0, stream>>>(x, W_conv, W_in, W_out, wcb, wib, wob, xbf, h0, h1);
  proj_in_gemm<<<dim3(NTOT / 128, HID_ / 128), 256, 0, stream>>>(xbf, wib, b_in, h0);
  const u16* cin = h0;
  u16* cout = h1;
  for (int s = 0; s < NSTEP; ++s) {
    conv_gemm4<<<dim3(NTOT / 256, 2), 512, 131072, stream>>>(cin, cout, wcb, b_conv);
    u16* t = (u16*)cin; cin = cout; cout = t;
  }
  proj_out_gemm<<<NTOT / 128, 256, 0, stream>>>(cin, wob, b_out, out);
}